// Round 2
// baseline (926.847 us; speedup 1.0000x reference)
//
#include <hip/hip_runtime.h>
#include <hip/hip_bf16.h>
#include <math.h>

// ViT block, B=32 S=256 D=768 H=12 HD=64 MLP=3072. fp32 I/O (reference dtype),
// bf16 MFMA internally for the two MLP GEMMs. Threshold: 0.108 absmax (2% rel).
//
// ws layout (total 97,812,480 B):
//   [0,        25165824)  out1 fp32 [8192][768]  attn+x residual trunk
//   [25165824, 37748736)  q  bf16 [B,H,S,64] ; reused as h2 bf16 [8192][768]
//   [37748736, 50331648)  k  bf16             ; overlaid by mb after attn
//   [50331648, 62914560)  v  bf16             ; overlaid by mb after attn
//   [37748736, 88080384)  mb bf16 [8192][3072] gelu(fc1)
//   [88080384, 88178688)  Wqb bf16 [12][64][64]
//   [88178688, 88276992)  Wkb bf16
//   [88276992, 88375296)  Wvb bf16
//   [88375296, 93093888)  W1b bf16 [3072][768]
//   [93093888, 97812480)  W2b bf16 [768][3072]

static constexpr int Bn = 32, Sn = 256, Dn = 768, Hn = 12, HDn = 64, MLPn = 3072;
static constexpr int NT = Bn * Sn; // 8192 tokens

typedef unsigned short ushort_t;
typedef unsigned int u32;
typedef __attribute__((ext_vector_type(8))) short short8; // 8 bf16 MFMA A/B frag
typedef __attribute__((ext_vector_type(4))) float f32x4;  // MFMA C/D frag

__device__ __forceinline__ float bflo(u32 w) { return __uint_as_float(w << 16); }
__device__ __forceinline__ float bfhi(u32 w) { return __uint_as_float(w & 0xffff0000u); }
__device__ __forceinline__ ushort_t f2bf(float f) { // round-to-nearest-even
  u32 u = __float_as_uint(f);
  u += 0x7fffu + ((u >> 16) & 1u);
  return (ushort_t)(u >> 16);
}

// ---------------- kernel 0: fp32 -> bf16 weight conversion ---------------------
__global__ __launch_bounds__(256) void k_f2bf(const float* __restrict__ src,
                                              ushort_t* __restrict__ dst, int n4) {
  int i = blockIdx.x * 256 + threadIdx.x;
  if (i < n4) {
    float4 v = ((const float4*)src)[i];
    ushort4 o;
    o.x = f2bf(v.x); o.y = f2bf(v.y); o.z = f2bf(v.z); o.w = f2bf(v.w);
    ((ushort4*)dst)[i] = o;
  }
}

// ---------------- kernel 1: LN1 + per-head QKV projection (one WG per token) ----
__global__ __launch_bounds__(256) void k_ln1_qkv(
    const float* __restrict__ x,
    const float* __restrict__ g1, const float* __restrict__ be1,
    const ushort_t* __restrict__ Wq, const float* __restrict__ bq,
    const ushort_t* __restrict__ Wk, const float* __restrict__ bk,
    const ushort_t* __restrict__ Wv, const float* __restrict__ bv,
    ushort_t* __restrict__ qo, ushort_t* __restrict__ ko, ushort_t* __restrict__ vo)
{
  const int t = blockIdx.x;
  const int tid = threadIdx.x;
  __shared__ float hln[Dn];
  __shared__ float red[8];

  float xv[3];
#pragma unroll
  for (int i = 0; i < 3; i++) xv[i] = x[(size_t)t * Dn + tid + i * 256];
  float s = xv[0] + xv[1] + xv[2];
#pragma unroll
  for (int off = 32; off > 0; off >>= 1) s += __shfl_down(s, off, 64);
  if ((tid & 63) == 0) red[tid >> 6] = s;
  __syncthreads();
  float mean = (red[0] + red[1] + red[2] + red[3]) * (1.0f / 768.0f);
  float d0 = xv[0] - mean, d1 = xv[1] - mean, d2 = xv[2] - mean;
  float s2 = d0 * d0 + d1 * d1 + d2 * d2;
#pragma unroll
  for (int off = 32; off > 0; off >>= 1) s2 += __shfl_down(s2, off, 64);
  if ((tid & 63) == 0) red[4 + (tid >> 6)] = s2;
  __syncthreads();
  float rstd = rsqrtf((red[4] + red[5] + red[6] + red[7]) * (1.0f / 768.0f) + 1e-5f);
#pragma unroll
  for (int i = 0; i < 3; i++) {
    int d = tid + i * 256;
    hln[d] = (xv[i] - mean) * rstd * g1[d] + be1[d];
  }
  __syncthreads();

  const int b_ = t / Sn, s_ = t - b_ * Sn;
  // 2304 outputs (q,k,v x 768) -> 9 per thread; mat & head wave-uniform per i.
#pragma unroll
  for (int i = 0; i < 9; i++) {
    int o = tid + i * 256;
    int mat = o / 768;
    int c = o - mat * 768; // head*64 + e
    int head = c >> 6;
    const ushort_t* W; const float* bias; ushort_t* dst;
    if (mat == 0)      { W = Wq; bias = bq; dst = qo; }
    else if (mat == 1) { W = Wk; bias = bk; dst = ko; }
    else               { W = Wv; bias = bv; dst = vo; }
    const uint4* W4 = (const uint4*)(W + (size_t)c * 64); // W[head][e][0..63] bf16
    const float* hh = &hln[head << 6];
    float a0 = bias[c], a1 = 0.f, a2 = 0.f, a3 = 0.f;
#pragma unroll
    for (int jj = 0; jj < 8; jj++) {
      uint4 w = W4[jj];
      a0 += hh[jj * 8 + 0] * bflo(w.x); a1 += hh[jj * 8 + 1] * bfhi(w.x);
      a2 += hh[jj * 8 + 2] * bflo(w.y); a3 += hh[jj * 8 + 3] * bfhi(w.y);
      a0 += hh[jj * 8 + 4] * bflo(w.z); a1 += hh[jj * 8 + 5] * bfhi(w.z);
      a2 += hh[jj * 8 + 6] * bflo(w.w); a3 += hh[jj * 8 + 7] * bfhi(w.w);
    }
    dst[(((size_t)b_ * Hn + head) * Sn + s_) * HDn + (c & 63)] = f2bf((a0 + a1) + (a2 + a3));
  }
}

// ---------------- kernel 2: attention (one WG per (b,h), thread = query row) ----
// K,V staged in LDS as bf16 (64KB). Online softmax, fused +x -> out1 (fp32).
__global__ __launch_bounds__(256) void k_attn(
    const ushort_t* __restrict__ q, const ushort_t* __restrict__ k,
    const ushort_t* __restrict__ v, const float* __restrict__ x,
    float* __restrict__ out1)
{
  __shared__ __align__(16) ushort_t Ks[Sn * HDn];
  __shared__ __align__(16) ushort_t Vs[Sn * HDn];
  const int bh = blockIdx.x;
  const int b_ = bh / Hn, h_ = bh - b_ * Hn;
  const int t = threadIdx.x;

  {
    const uint4* kg = (const uint4*)(k + (size_t)bh * Sn * HDn);
    const uint4* vg = (const uint4*)(v + (size_t)bh * Sn * HDn);
    uint4* sk = (uint4*)Ks; uint4* sv = (uint4*)Vs;
#pragma unroll
    for (int i = 0; i < 8; i++) { sk[t + i * 256] = kg[t + i * 256]; sv[t + i * 256] = vg[t + i * 256]; }
  }
  float qr[64];
  {
    const uint4* qg = (const uint4*)(q + ((size_t)bh * Sn + t) * HDn);
#pragma unroll
    for (int i = 0; i < 8; i++) {
      uint4 w = qg[i];
      qr[i * 8 + 0] = bflo(w.x) * 0.125f; qr[i * 8 + 1] = bfhi(w.x) * 0.125f;
      qr[i * 8 + 2] = bflo(w.y) * 0.125f; qr[i * 8 + 3] = bfhi(w.y) * 0.125f;
      qr[i * 8 + 4] = bflo(w.z) * 0.125f; qr[i * 8 + 5] = bfhi(w.z) * 0.125f;
      qr[i * 8 + 6] = bflo(w.w) * 0.125f; qr[i * 8 + 7] = bfhi(w.w) * 0.125f;
    }
  }
  __syncthreads();

  float mx = -3.0e38f, l = 0.f;
  float acc[64];
#pragma unroll
  for (int e = 0; e < 64; e++) acc[e] = 0.f;

  for (int j = 0; j < Sn; j++) {
    const uint4* Kr = (const uint4*)Ks + j * 8;
    float s0 = 0, s1 = 0, s2 = 0, s3 = 0;
#pragma unroll
    for (int i = 0; i < 8; i++) {
      uint4 w = Kr[i];
      s0 += qr[i * 8 + 0] * bflo(w.x); s1 += qr[i * 8 + 1] * bfhi(w.x);
      s2 += qr[i * 8 + 2] * bflo(w.y); s3 += qr[i * 8 + 3] * bfhi(w.y);
      s0 += qr[i * 8 + 4] * bflo(w.z); s1 += qr[i * 8 + 5] * bfhi(w.z);
      s2 += qr[i * 8 + 6] * bflo(w.w); s3 += qr[i * 8 + 7] * bfhi(w.w);
    }
    float sc = (s0 + s1) + (s2 + s3);
    float mn = fmaxf(mx, sc);
    float alpha = __expf(mx - mn);
    float p = __expf(sc - mn);
    l = l * alpha + p;
    mx = mn;
    const uint4* Vr = (const uint4*)Vs + j * 8;
#pragma unroll
    for (int i = 0; i < 8; i++) {
      uint4 w = Vr[i];
      acc[i * 8 + 0] = acc[i * 8 + 0] * alpha + p * bflo(w.x);
      acc[i * 8 + 1] = acc[i * 8 + 1] * alpha + p * bfhi(w.x);
      acc[i * 8 + 2] = acc[i * 8 + 2] * alpha + p * bflo(w.y);
      acc[i * 8 + 3] = acc[i * 8 + 3] * alpha + p * bfhi(w.y);
      acc[i * 8 + 4] = acc[i * 8 + 4] * alpha + p * bflo(w.z);
      acc[i * 8 + 5] = acc[i * 8 + 5] * alpha + p * bfhi(w.z);
      acc[i * 8 + 6] = acc[i * 8 + 6] * alpha + p * bflo(w.w);
      acc[i * 8 + 7] = acc[i * 8 + 7] * alpha + p * bfhi(w.w);
    }
  }

  float rl = 1.0f / l;
  float* o = out1 + ((size_t)(b_ * Sn + t)) * Dn + h_ * HDn;
  const float* xr = x + ((size_t)(b_ * Sn + t)) * Dn + h_ * HDn;
#pragma unroll
  for (int e = 0; e < 64; e += 4) {
    float4 xv = *(const float4*)(xr + e);
    float4 ov;
    ov.x = acc[e + 0] * rl + xv.x;
    ov.y = acc[e + 1] * rl + xv.y;
    ov.z = acc[e + 2] * rl + xv.z;
    ov.w = acc[e + 3] * rl + xv.w;
    *(float4*)(o + e) = ov;
  }
}

// ---------------- kernel 3: LN2 (one WG per token) -----------------------------
__global__ __launch_bounds__(256) void k_ln2(
    const float* __restrict__ in, const float* __restrict__ g2,
    const float* __restrict__ be2, ushort_t* __restrict__ h2)
{
  const int t = blockIdx.x, tid = threadIdx.x;
  __shared__ float red[8];
  float xv[3];
#pragma unroll
  for (int i = 0; i < 3; i++) xv[i] = in[(size_t)t * Dn + tid + i * 256];
  float s = xv[0] + xv[1] + xv[2];
#pragma unroll
  for (int off = 32; off > 0; off >>= 1) s += __shfl_down(s, off, 64);
  if ((tid & 63) == 0) red[tid >> 6] = s;
  __syncthreads();
  float mean = (red[0] + red[1] + red[2] + red[3]) * (1.0f / 768.0f);
  float d0 = xv[0] - mean, d1 = xv[1] - mean, d2 = xv[2] - mean;
  float s2 = d0 * d0 + d1 * d1 + d2 * d2;
#pragma unroll
  for (int off = 32; off > 0; off >>= 1) s2 += __shfl_down(s2, off, 64);
  if ((tid & 63) == 0) red[4 + (tid >> 6)] = s2;
  __syncthreads();
  float rstd = rsqrtf((red[4] + red[5] + red[6] + red[7]) * (1.0f / 768.0f) + 1e-5f);
#pragma unroll
  for (int i = 0; i < 3; i++) {
    int d = tid + i * 256;
    h2[(size_t)t * Dn + d] = f2bf((xv[i] - mean) * rstd * g2[d] + be2[d]);
  }
}

// ---------------- kernels 4/5: bf16 MFMA GEMM, C[M,N] = A[M,K] * B[N,K]^T ------
// Block 128x128, BK=32, 256 threads = 4 waves in 2x2; each wave 64x64 as 4x4
// mfma_f32_16x16x32_bf16 tiles. Verified layouts (learn_hip m89/m91):
//   A/B frag: [row = lane&15][k = (lane>>4)*8 + j]; C/D: col=lane&15, row=quad*4+r.
// GELU=true: exact-erf GELU epilogue, bf16 out (CoutB). GELU=false: +bias+res, fp32 out.
template <int KDIM, bool GELU>
__global__ __launch_bounds__(256) void k_gemm_bt(
    const ushort_t* __restrict__ A,   // [M][KDIM] bf16
    const ushort_t* __restrict__ Bw,  // [N][KDIM] bf16
    const float* __restrict__ bias,   // [N] fp32
    const float* __restrict__ res,    // [M][N] fp32 residual (GELU=false only)
    ushort_t* __restrict__ CoutB,     // bf16 out (GELU=true)
    float* __restrict__ CoutF,        // fp32 out (GELU=false)
    int N)
{
  __shared__ __align__(16) ushort_t As[128 * 32];
  __shared__ __align__(16) ushort_t Bs[128 * 32];
  const int tid = threadIdx.x;
  const int m0 = blockIdx.y * 128, n0 = blockIdx.x * 128;
  const int wave = tid >> 6, lane = tid & 63;
  const int wm = (wave >> 1) << 6, wn = (wave & 1) << 6;
  const int lrow = lane & 15, quad = lane >> 4;
  const int arow = tid >> 1, aseg = (tid & 1) << 4; // 16 bf16 per thread per tile

  f32x4 acc[4][4];
#pragma unroll
  for (int mi = 0; mi < 4; mi++)
#pragma unroll
    for (int ni = 0; ni < 4; ni++) acc[mi][ni] = (f32x4){0.f, 0.f, 0.f, 0.f};

  const uint4* gA = (const uint4*)(A + (size_t)(m0 + arow) * KDIM + aseg);
  const uint4* gB = (const uint4*)(Bw + (size_t)(n0 + arow) * KDIM + aseg);
  uint4* sA = (uint4*)(As + arow * 32 + aseg);
  uint4* sB = (uint4*)(Bs + arow * 32 + aseg);

  for (int k0 = 0; k0 < KDIM; k0 += 32) {
    uint4 a0 = gA[0], a1 = gA[1];
    uint4 b0 = gB[0], b1 = gB[1];
    gA += 4; gB += 4; // advance 32 bf16
    sA[0] = a0; sA[1] = a1;
    sB[0] = b0; sB[1] = b1;
    __syncthreads();
    short8 af[4], bfv[4];
#pragma unroll
    for (int mi = 0; mi < 4; mi++)
      af[mi] = *(const short8*)(As + (wm + mi * 16 + lrow) * 32 + quad * 8);
#pragma unroll
    for (int ni = 0; ni < 4; ni++)
      bfv[ni] = *(const short8*)(Bs + (wn + ni * 16 + lrow) * 32 + quad * 8);
#pragma unroll
    for (int mi = 0; mi < 4; mi++)
#pragma unroll
      for (int ni = 0; ni < 4; ni++)
        acc[mi][ni] = __builtin_amdgcn_mfma_f32_16x16x32_bf16(af[mi], bfv[ni], acc[mi][ni], 0, 0, 0);
    __syncthreads();
  }

#pragma unroll
  for (int ni = 0; ni < 4; ni++) {
    int col = n0 + wn + ni * 16 + lrow;
    float bc = bias[col];
#pragma unroll
    for (int mi = 0; mi < 4; mi++) {
#pragma unroll
      for (int r = 0; r < 4; r++) {
        int row = m0 + wm + mi * 16 + quad * 4 + r;
        float vv = acc[mi][ni][r] + bc;
        if (GELU) {
          float o = 0.5f * vv * (1.0f + erff(vv * 0.70710678f));
          CoutB[(size_t)row * N + col] = f2bf(o);
        } else {
          CoutF[(size_t)row * N + col] = vv + res[(size_t)row * N + col];
        }
      }
    }
  }
}

// ---------------- launch --------------------------------------------------------
extern "C" void kernel_launch(void* const* d_in, const int* in_sizes, int n_in,
                              void* d_out, int out_size, void* d_ws, size_t ws_size,
                              hipStream_t stream) {
  (void)in_sizes; (void)n_in; (void)out_size; (void)ws_size;
  const float* x   = (const float*)d_in[0];
  const float* g1  = (const float*)d_in[1];
  const float* be1 = (const float*)d_in[2];
  const float* Wq  = (const float*)d_in[3];
  const float* bq  = (const float*)d_in[4];
  const float* Wk  = (const float*)d_in[5];
  const float* bk  = (const float*)d_in[6];
  const float* Wv  = (const float*)d_in[7];
  const float* bv  = (const float*)d_in[8];
  const float* g2  = (const float*)d_in[9];
  const float* be2 = (const float*)d_in[10];
  const float* W1  = (const float*)d_in[11];
  const float* bm1 = (const float*)d_in[12];
  const float* W2  = (const float*)d_in[13];
  const float* bm2 = (const float*)d_in[14];
  float* outp = (float*)d_out;

  char* ws = (char*)d_ws;
  float*    out1 = (float*)ws;                               // 25165824 B
  ushort_t* qb   = (ushort_t*)(ws + 25165824);
  ushort_t* kb   = (ushort_t*)(ws + 37748736);
  ushort_t* vb   = (ushort_t*)(ws + 50331648);
  ushort_t* h2   = qb;                                       // reuse q after attn
  ushort_t* mb   = (ushort_t*)(ws + 37748736);               // overlays k,v
  ushort_t* Wqb  = (ushort_t*)(ws + 88080384);
  ushort_t* Wkb  = (ushort_t*)(ws + 88178688);
  ushort_t* Wvb  = (ushort_t*)(ws + 88276992);
  ushort_t* W1b  = (ushort_t*)(ws + 88375296);
  ushort_t* W2b  = (ushort_t*)(ws + 93093888);

  const int nW  = Hn * HDn * HDn;     // 49152
  const int nW1 = MLPn * Dn;          // 2359296
  k_f2bf<<<dim3(nW / 4 / 256), dim3(256), 0, stream>>>(Wq, Wqb, nW / 4);
  k_f2bf<<<dim3(nW / 4 / 256), dim3(256), 0, stream>>>(Wk, Wkb, nW / 4);
  k_f2bf<<<dim3(nW / 4 / 256), dim3(256), 0, stream>>>(Wv, Wvb, nW / 4);
  k_f2bf<<<dim3(nW1 / 4 / 256), dim3(256), 0, stream>>>(W1, W1b, nW1 / 4);
  k_f2bf<<<dim3(nW1 / 4 / 256), dim3(256), 0, stream>>>(W2, W2b, nW1 / 4);

  k_ln1_qkv<<<dim3(NT), dim3(256), 0, stream>>>(x, g1, be1, Wqb, bq, Wkb, bk, Wvb, bv, qb, kb, vb);
  k_attn<<<dim3(Bn * Hn), dim3(256), 0, stream>>>(qb, kb, vb, x, out1);
  k_ln2<<<dim3(NT), dim3(256), 0, stream>>>(out1, g2, be2, h2);
  k_gemm_bt<Dn, true><<<dim3(MLPn / 128, NT / 128), dim3(256), 0, stream>>>(h2, W1b, bm1, nullptr, mb, nullptr, MLPn);
  k_gemm_bt<MLPn, false><<<dim3(Dn / 128, NT / 128), dim3(256), 0, stream>>>(mb, W2b, bm2, out1, nullptr, outp, Dn);
}

// Round 3
// 653.525 us; speedup vs baseline: 1.4182x; 1.4182x over previous
//
#include <hip/hip_runtime.h>
#include <hip/hip_bf16.h>
#include <math.h>

// ViT block, B=32 S=256 D=768 H=12 HD=64 MLP=3072. fp32 I/O, bf16 MFMA inside.
//
// ws layout (total ~97.9 MB):
//   [0,        25165824)  out1 fp32 [8192][768] residual trunk; hb bf16 [8192][768]
//                         lives here BEFORE attn (freed when attn writes out1)
//   [25165824, 37748736)  q  bf16 [B,H,S,64] ; reused as h2 bf16 after attn
//   [37748736, 50331648)  k  bf16             ; overlaid by mb after attn
//   [50331648, 62914560)  v  bf16             ; overlaid by mb after attn
//   [37748736, 88080384)  mb bf16 [8192][3072] gelu(fc1)
//   [88080384, 88375296)  Wc  bf16 [12][192][64] packed qkv weights
//   [88375296, 93093888)  W1b bf16 [3072][768]
//   [93093888, 97812480)  W2b bf16 [768][3072]
//   [97812480, 97821696)  bcb fp32 [12][192] packed qkv bias

static constexpr int Bn = 32, Sn = 256, Dn = 768, Hn = 12, HDn = 64, MLPn = 3072;
static constexpr int NT = Bn * Sn; // 8192 tokens

typedef unsigned short ushort_t;
typedef unsigned int u32;
typedef __attribute__((ext_vector_type(8))) short short8; // 8 bf16 MFMA A/B frag
typedef __attribute__((ext_vector_type(4))) float f32x4;  // MFMA C/D frag

__device__ __forceinline__ float bflo(u32 w) { return __uint_as_float(w << 16); }
__device__ __forceinline__ float bfhi(u32 w) { return __uint_as_float(w & 0xffff0000u); }
__device__ __forceinline__ ushort_t f2bf(float f) { // round-to-nearest-even
  u32 u = __float_as_uint(f);
  u += 0x7fffu + ((u >> 16) & 1u);
  return (ushort_t)(u >> 16);
}

// ---------------- fp32 -> bf16 bulk conversion ---------------------------------
__global__ __launch_bounds__(256) void k_f2bf(const float* __restrict__ src,
                                              ushort_t* __restrict__ dst, int n4) {
  int i = blockIdx.x * 256 + threadIdx.x;
  if (i < n4) {
    float4 v = ((const float4*)src)[i];
    ushort4 o;
    o.x = f2bf(v.x); o.y = f2bf(v.y); o.z = f2bf(v.z); o.w = f2bf(v.w);
    ((ushort4*)dst)[i] = o;
  }
}

// ---------------- pack qkv weights [12][3*64][64] bf16 + bias [12][192] fp32 ----
__global__ __launch_bounds__(256) void k_pack_qkv(
    const float* __restrict__ Wq, const float* __restrict__ Wk,
    const float* __restrict__ Wv, const float* __restrict__ bq,
    const float* __restrict__ bk, const float* __restrict__ bv,
    ushort_t* __restrict__ Wc, float* __restrict__ bc)
{
  int i = blockIdx.x * 256 + threadIdx.x; // 0 .. 147455
  int h = i / 12288, rem = i - h * 12288;
  int mat = rem / 4096, w = rem - mat * 4096;
  const float* src = (mat == 0) ? Wq : ((mat == 1) ? Wk : Wv);
  Wc[i] = f2bf(src[h * 4096 + w]);
  if (i < Hn * 192) {
    int h2 = i / 192, r2 = i - h2 * 192;
    int m2 = r2 / 64, e2 = r2 - m2 * 64;
    const float* bs = (m2 == 0) ? bq : ((m2 == 1) ? bk : bv);
    bc[i] = bs[h2 * 64 + e2];
  }
}

// ---------------- kernel 1: LN1 -> bf16 (one WG per token) ---------------------
__global__ __launch_bounds__(256) void k_ln1(
    const float* __restrict__ x, const float* __restrict__ g1,
    const float* __restrict__ be1, ushort_t* __restrict__ hb)
{
  const int t = blockIdx.x, tid = threadIdx.x;
  __shared__ float red[8];
  float xv[3];
#pragma unroll
  for (int i = 0; i < 3; i++) xv[i] = x[(size_t)t * Dn + tid + i * 256];
  float s = xv[0] + xv[1] + xv[2];
#pragma unroll
  for (int off = 32; off > 0; off >>= 1) s += __shfl_down(s, off, 64);
  if ((tid & 63) == 0) red[tid >> 6] = s;
  __syncthreads();
  float mean = (red[0] + red[1] + red[2] + red[3]) * (1.0f / 768.0f);
  float d0 = xv[0] - mean, d1 = xv[1] - mean, d2 = xv[2] - mean;
  float s2 = d0 * d0 + d1 * d1 + d2 * d2;
#pragma unroll
  for (int off = 32; off > 0; off >>= 1) s2 += __shfl_down(s2, off, 64);
  if ((tid & 63) == 0) red[4 + (tid >> 6)] = s2;
  __syncthreads();
  float rstd = rsqrtf((red[4] + red[5] + red[6] + red[7]) * (1.0f / 768.0f) + 1e-5f);
#pragma unroll
  for (int i = 0; i < 3; i++) {
    int d = tid + i * 256;
    hb[(size_t)t * Dn + d] = f2bf((xv[i] - mean) * rstd * g1[d] + be1[d]);
  }
}

// ---------------- kernel 2: QKV projection via MFMA ----------------------------
// One WG per (b, head, token-half): M=128 tokens, N=192 (q|k|v), K=64.
// 4 waves 2x2: wave covers M=64, N=96 as 4x6 16x16 tiles, K=64 = 2 mfma steps.
__global__ __launch_bounds__(256) void k_qkv(
    const ushort_t* __restrict__ hb,  // [NT][768] bf16
    const ushort_t* __restrict__ Wc,  // [12][192][64] bf16
    const float* __restrict__ bc,     // [12][192] fp32
    ushort_t* __restrict__ qo, ushort_t* __restrict__ ko, ushort_t* __restrict__ vo)
{
  __shared__ __align__(16) ushort_t As[128 * 72]; // stride 72: 2-way banks only
  __shared__ __align__(16) ushort_t Ws[192 * 72];
  const int blk = blockIdx.x;         // (b*12 + h)*2 + half
  const int half = blk & 1;
  const int bh = blk >> 1;
  const int b_ = bh / Hn, h_ = bh - b_ * Hn;
  const int tid = threadIdx.x;
  const int t0 = b_ * Sn + half * 128;

  { // stage A: 128 rows x 64 cols (head slice of hb)
    int row = tid >> 1, seg = (tid & 1) * 32;
    const uint4* g = (const uint4*)(hb + (size_t)(t0 + row) * Dn + h_ * 64 + seg);
    uint4* s = (uint4*)(As + row * 72 + seg);
    s[0] = g[0]; s[1] = g[1]; s[2] = g[2]; s[3] = g[3];
  }
  { // stage W: 192 rows x 64 cols, contiguous per head
    int rr = tid >> 2, seg = (tid & 3) * 16;
    const ushort_t* gw = Wc + h_ * 12288;
#pragma unroll
    for (int p = 0; p < 3; p++) {
      int R = p * 64 + rr;
      const uint4* g = (const uint4*)(gw + R * 64 + seg);
      uint4* s = (uint4*)(Ws + R * 72 + seg);
      s[0] = g[0]; s[1] = g[1];
    }
  }
  __syncthreads();

  const int wave = tid >> 6, lane = tid & 63;
  const int wm = (wave >> 1) * 64, wn = (wave & 1) * 96;
  const int lrow = lane & 15, quad = lane >> 4;

  f32x4 acc[4][6];
#pragma unroll
  for (int mi = 0; mi < 4; mi++)
#pragma unroll
    for (int ni = 0; ni < 6; ni++) acc[mi][ni] = (f32x4){0.f, 0.f, 0.f, 0.f};

#pragma unroll
  for (int kk = 0; kk < 2; kk++) {
    short8 af[4], wf[6];
#pragma unroll
    for (int mi = 0; mi < 4; mi++)
      af[mi] = *(const short8*)(As + (wm + mi * 16 + lrow) * 72 + kk * 32 + quad * 8);
#pragma unroll
    for (int ni = 0; ni < 6; ni++)
      wf[ni] = *(const short8*)(Ws + (wn + ni * 16 + lrow) * 72 + kk * 32 + quad * 8);
#pragma unroll
    for (int mi = 0; mi < 4; mi++)
#pragma unroll
      for (int ni = 0; ni < 6; ni++)
        acc[mi][ni] = __builtin_amdgcn_mfma_f32_16x16x32_bf16(af[mi], wf[ni], acc[mi][ni], 0, 0, 0);
  }

#pragma unroll
  for (int ni = 0; ni < 6; ni++) {
    int c = wn + ni * 16 + lrow;        // 0..191, mat uniform per (wave,ni)
    int mat = c >> 6, e = c & 63;
    float bb = bc[h_ * 192 + c];
    ushort_t* dst = (mat == 0) ? qo : ((mat == 1) ? ko : vo);
    size_t base = (((size_t)bh) * Sn + half * 128 + wm) * HDn + e;
#pragma unroll
    for (int mi = 0; mi < 4; mi++) {
#pragma unroll
      for (int r = 0; r < 4; r++) {
        int lr = mi * 16 + quad * 4 + r;
        dst[base + (size_t)lr * HDn] = f2bf(acc[mi][ni][r] + bb);
      }
    }
  }
}

// ---------------- kernel 3: attention (one WG per (b,h), thread = query row) ----
__global__ __launch_bounds__(256) void k_attn(
    const ushort_t* __restrict__ q, const ushort_t* __restrict__ k,
    const ushort_t* __restrict__ v, const float* __restrict__ x,
    float* __restrict__ out1)
{
  __shared__ __align__(16) ushort_t Ks[Sn * HDn];
  __shared__ __align__(16) ushort_t Vs[Sn * HDn];
  const int bh = blockIdx.x;
  const int b_ = bh / Hn, h_ = bh - b_ * Hn;
  const int t = threadIdx.x;

  {
    const uint4* kg = (const uint4*)(k + (size_t)bh * Sn * HDn);
    const uint4* vg = (const uint4*)(v + (size_t)bh * Sn * HDn);
    uint4* sk = (uint4*)Ks; uint4* sv = (uint4*)Vs;
#pragma unroll
    for (int i = 0; i < 8; i++) { sk[t + i * 256] = kg[t + i * 256]; sv[t + i * 256] = vg[t + i * 256]; }
  }
  float qr[64];
  {
    const uint4* qg = (const uint4*)(q + ((size_t)bh * Sn + t) * HDn);
#pragma unroll
    for (int i = 0; i < 8; i++) {
      uint4 w = qg[i];
      qr[i * 8 + 0] = bflo(w.x) * 0.125f; qr[i * 8 + 1] = bfhi(w.x) * 0.125f;
      qr[i * 8 + 2] = bflo(w.y) * 0.125f; qr[i * 8 + 3] = bfhi(w.y) * 0.125f;
      qr[i * 8 + 4] = bflo(w.z) * 0.125f; qr[i * 8 + 5] = bfhi(w.z) * 0.125f;
      qr[i * 8 + 6] = bflo(w.w) * 0.125f; qr[i * 8 + 7] = bfhi(w.w) * 0.125f;
    }
  }
  __syncthreads();

  float mx = -3.0e38f, l = 0.f;
  float acc[64];
#pragma unroll
  for (int e = 0; e < 64; e++) acc[e] = 0.f;

  for (int j = 0; j < Sn; j++) {
    const uint4* Kr = (const uint4*)Ks + j * 8;
    float s0 = 0, s1 = 0, s2 = 0, s3 = 0;
#pragma unroll
    for (int i = 0; i < 8; i++) {
      uint4 w = Kr[i];
      s0 += qr[i * 8 + 0] * bflo(w.x); s1 += qr[i * 8 + 1] * bfhi(w.x);
      s2 += qr[i * 8 + 2] * bflo(w.y); s3 += qr[i * 8 + 3] * bfhi(w.y);
      s0 += qr[i * 8 + 4] * bflo(w.z); s1 += qr[i * 8 + 5] * bfhi(w.z);
      s2 += qr[i * 8 + 6] * bflo(w.w); s3 += qr[i * 8 + 7] * bfhi(w.w);
    }
    float sc = (s0 + s1) + (s2 + s3);
    float mn = fmaxf(mx, sc);
    float alpha = __expf(mx - mn);
    float p = __expf(sc - mn);
    l = l * alpha + p;
    mx = mn;
    const uint4* Vr = (const uint4*)Vs + j * 8;
#pragma unroll
    for (int i = 0; i < 8; i++) {
      uint4 w = Vr[i];
      acc[i * 8 + 0] = acc[i * 8 + 0] * alpha + p * bflo(w.x);
      acc[i * 8 + 1] = acc[i * 8 + 1] * alpha + p * bfhi(w.x);
      acc[i * 8 + 2] = acc[i * 8 + 2] * alpha + p * bflo(w.y);
      acc[i * 8 + 3] = acc[i * 8 + 3] * alpha + p * bfhi(w.y);
      acc[i * 8 + 4] = acc[i * 8 + 4] * alpha + p * bflo(w.z);
      acc[i * 8 + 5] = acc[i * 8 + 5] * alpha + p * bfhi(w.z);
      acc[i * 8 + 6] = acc[i * 8 + 6] * alpha + p * bflo(w.w);
      acc[i * 8 + 7] = acc[i * 8 + 7] * alpha + p * bfhi(w.w);
    }
  }

  float rl = 1.0f / l;
  float* o = out1 + ((size_t)(b_ * Sn + t)) * Dn + h_ * HDn;
  const float* xr = x + ((size_t)(b_ * Sn + t)) * Dn + h_ * HDn;
#pragma unroll
  for (int e = 0; e < 64; e += 4) {
    float4 xv = *(const float4*)(xr + e);
    float4 ov;
    ov.x = acc[e + 0] * rl + xv.x;
    ov.y = acc[e + 1] * rl + xv.y;
    ov.z = acc[e + 2] * rl + xv.z;
    ov.w = acc[e + 3] * rl + xv.w;
    *(float4*)(o + e) = ov;
  }
}

// ---------------- kernel 4: LN2 (one WG per token) -----------------------------
__global__ __launch_bounds__(256) void k_ln2(
    const float* __restrict__ in, const float* __restrict__ g2,
    const float* __restrict__ be2, ushort_t* __restrict__ h2)
{
  const int t = blockIdx.x, tid = threadIdx.x;
  __shared__ float red[8];
  float xv[3];
#pragma unroll
  for (int i = 0; i < 3; i++) xv[i] = in[(size_t)t * Dn + tid + i * 256];
  float s = xv[0] + xv[1] + xv[2];
#pragma unroll
  for (int off = 32; off > 0; off >>= 1) s += __shfl_down(s, off, 64);
  if ((tid & 63) == 0) red[tid >> 6] = s;
  __syncthreads();
  float mean = (red[0] + red[1] + red[2] + red[3]) * (1.0f / 768.0f);
  float d0 = xv[0] - mean, d1 = xv[1] - mean, d2 = xv[2] - mean;
  float s2 = d0 * d0 + d1 * d1 + d2 * d2;
#pragma unroll
  for (int off = 32; off > 0; off >>= 1) s2 += __shfl_down(s2, off, 64);
  if ((tid & 63) == 0) red[4 + (tid >> 6)] = s2;
  __syncthreads();
  float rstd = rsqrtf((red[4] + red[5] + red[6] + red[7]) * (1.0f / 768.0f) + 1e-5f);
#pragma unroll
  for (int i = 0; i < 3; i++) {
    int d = tid + i * 256;
    h2[(size_t)t * Dn + d] = f2bf((xv[i] - mean) * rstd * g2[d] + be2[d]);
  }
}

// ---------------- kernels 5/6: bf16 MFMA GEMM, C[M,N] = A[M,K] * B[N,K]^T ------
// Block 128x128, BK=32, 4 waves 2x2, each wave 64x64 as 4x4 16x16x32 tiles.
// LDS stride 40 (pad 8): frag-read banks 20*row mod 32 -> 2-way only (free).
template <int KDIM, bool GELU>
__global__ __launch_bounds__(256) void k_gemm_bt(
    const ushort_t* __restrict__ A,   // [M][KDIM] bf16
    const ushort_t* __restrict__ Bw,  // [N][KDIM] bf16
    const float* __restrict__ bias,   // [N] fp32
    const float* __restrict__ res,    // [M][N] fp32 residual (GELU=false only)
    ushort_t* __restrict__ CoutB,     // bf16 out (GELU=true)
    float* __restrict__ CoutF,        // fp32 out (GELU=false)
    int N)
{
  __shared__ __align__(16) ushort_t As[128 * 40];
  __shared__ __align__(16) ushort_t Bs[128 * 40];
  const int tid = threadIdx.x;
  const int m0 = blockIdx.y * 128, n0 = blockIdx.x * 128;
  const int wave = tid >> 6, lane = tid & 63;
  const int wm = (wave >> 1) << 6, wn = (wave & 1) << 6;
  const int lrow = lane & 15, quad = lane >> 4;
  const int arow = tid >> 1, aseg = (tid & 1) << 4; // 16 bf16 per thread per tile

  f32x4 acc[4][4];
#pragma unroll
  for (int mi = 0; mi < 4; mi++)
#pragma unroll
    for (int ni = 0; ni < 4; ni++) acc[mi][ni] = (f32x4){0.f, 0.f, 0.f, 0.f};

  const uint4* gA = (const uint4*)(A + (size_t)(m0 + arow) * KDIM + aseg);
  const uint4* gB = (const uint4*)(Bw + (size_t)(n0 + arow) * KDIM + aseg);
  uint4* sA = (uint4*)(As + arow * 40 + aseg);
  uint4* sB = (uint4*)(Bs + arow * 40 + aseg);

  for (int k0 = 0; k0 < KDIM; k0 += 32) {
    uint4 a0 = gA[0], a1 = gA[1];
    uint4 b0 = gB[0], b1 = gB[1];
    gA += 4; gB += 4; // advance 32 bf16
    sA[0] = a0; sA[1] = a1;
    sB[0] = b0; sB[1] = b1;
    __syncthreads();
    short8 af[4], bfv[4];
#pragma unroll
    for (int mi = 0; mi < 4; mi++)
      af[mi] = *(const short8*)(As + (wm + mi * 16 + lrow) * 40 + quad * 8);
#pragma unroll
    for (int ni = 0; ni < 4; ni++)
      bfv[ni] = *(const short8*)(Bs + (wn + ni * 16 + lrow) * 40 + quad * 8);
#pragma unroll
    for (int mi = 0; mi < 4; mi++)
#pragma unroll
      for (int ni = 0; ni < 4; ni++)
        acc[mi][ni] = __builtin_amdgcn_mfma_f32_16x16x32_bf16(af[mi], bfv[ni], acc[mi][ni], 0, 0, 0);
    __syncthreads();
  }

#pragma unroll
  for (int ni = 0; ni < 4; ni++) {
    int col = n0 + wn + ni * 16 + lrow;
    float bc = bias[col];
#pragma unroll
    for (int mi = 0; mi < 4; mi++) {
#pragma unroll
      for (int r = 0; r < 4; r++) {
        int row = m0 + wm + mi * 16 + quad * 4 + r;
        float vv = acc[mi][ni][r] + bc;
        if (GELU) {
          float o = 0.5f * vv * (1.0f + erff(vv * 0.70710678f));
          CoutB[(size_t)row * N + col] = f2bf(o);
        } else {
          CoutF[(size_t)row * N + col] = vv + res[(size_t)row * N + col];
        }
      }
    }
  }
}

// ---------------- launch --------------------------------------------------------
extern "C" void kernel_launch(void* const* d_in, const int* in_sizes, int n_in,
                              void* d_out, int out_size, void* d_ws, size_t ws_size,
                              hipStream_t stream) {
  (void)in_sizes; (void)n_in; (void)out_size; (void)ws_size;
  const float* x   = (const float*)d_in[0];
  const float* g1  = (const float*)d_in[1];
  const float* be1 = (const float*)d_in[2];
  const float* Wq  = (const float*)d_in[3];
  const float* bq  = (const float*)d_in[4];
  const float* Wk  = (const float*)d_in[5];
  const float* bk  = (const float*)d_in[6];
  const float* Wv  = (const float*)d_in[7];
  const float* bv  = (const float*)d_in[8];
  const float* g2  = (const float*)d_in[9];
  const float* be2 = (const float*)d_in[10];
  const float* W1  = (const float*)d_in[11];
  const float* bm1 = (const float*)d_in[12];
  const float* W2  = (const float*)d_in[13];
  const float* bm2 = (const float*)d_in[14];
  float* outp = (float*)d_out;

  char* ws = (char*)d_ws;
  float*    out1 = (float*)ws;                   // [0, 25165824)
  ushort_t* hb   = (ushort_t*)ws;                // bf16 h, pre-attn only
  ushort_t* qb   = (ushort_t*)(ws + 25165824);
  ushort_t* kb   = (ushort_t*)(ws + 37748736);
  ushort_t* vb   = (ushort_t*)(ws + 50331648);
  ushort_t* h2   = qb;                           // reuse q after attn
  ushort_t* mb   = (ushort_t*)(ws + 37748736);   // overlays k,v
  ushort_t* Wc   = (ushort_t*)(ws + 88080384);
  ushort_t* W1b  = (ushort_t*)(ws + 88375296);
  ushort_t* W2b  = (ushort_t*)(ws + 93093888);
  float*    bcb  = (float*)(ws + 97812480);

  const int nW1 = MLPn * Dn; // 2359296
  k_pack_qkv<<<dim3(576), dim3(256), 0, stream>>>(Wq, Wk, Wv, bq, bk, bv, Wc, bcb);
  k_f2bf<<<dim3(nW1 / 4 / 256), dim3(256), 0, stream>>>(W1, W1b, nW1 / 4);
  k_f2bf<<<dim3(nW1 / 4 / 256), dim3(256), 0, stream>>>(W2, W2b, nW1 / 4);

  k_ln1<<<dim3(NT), dim3(256), 0, stream>>>(x, g1, be1, hb);
  k_qkv<<<dim3(Bn * Hn * 2), dim3(256), 0, stream>>>(hb, Wc, bcb, qb, kb, vb);
  k_attn<<<dim3(Bn * Hn), dim3(256), 0, stream>>>(qb, kb, vb, x, out1);
  k_ln2<<<dim3(NT), dim3(256), 0, stream>>>(out1, g2, be2, h2);
  k_gemm_bt<Dn, true><<<dim3(MLPn / 128, NT / 128), dim3(256), 0, stream>>>(h2, W1b, bm1, nullptr, mb, nullptr, MLPn);
  k_gemm_bt<MLPn, false><<<dim3(Dn / 128, NT / 128), dim3(256), 0, stream>>>(mb, W2b, bm2, out1, nullptr, outp, Dn);
}

// Round 4
// 412.549 us; speedup vs baseline: 2.2466x; 1.5841x over previous
//
#include <hip/hip_runtime.h>
#include <hip/hip_bf16.h>
#include <math.h>

// ViT block, B=32 S=256 D=768 H=12 HD=64 MLP=3072. fp32 I/O, bf16 MFMA inside.
//
// ws layout (total ~97.9 MB):
//   [0,        25165824)  out1 fp32 [8192][768] residual trunk; hb bf16 [8192][768]
//                         lives here BEFORE attn (freed when attn writes out1)
//   [25165824, 37748736)  q  bf16 [B,H,S,64] ; reused as h2 bf16 after attn
//   [37748736, 50331648)  k  bf16             ; overlaid by mb after attn
//   [50331648, 62914560)  vt bf16 [B,H,64,S]  TRANSPOSED ; overlaid by mb after attn
//   [37748736, 88080384)  mb bf16 [8192][3072] gelu(fc1)
//   [88080384, 88375296)  Wc  bf16 [12][192][64] packed qkv weights
//   [88375296, 93093888)  W1b bf16 [3072][768]
//   [93093888, 97812480)  W2b bf16 [768][3072]
//   [97812480, 97821696)  bcb fp32 [12][192] packed qkv bias

static constexpr int Bn = 32, Sn = 256, Dn = 768, Hn = 12, HDn = 64, MLPn = 3072;
static constexpr int NT = Bn * Sn; // 8192 tokens

typedef unsigned short ushort_t;
typedef unsigned int u32;
typedef __attribute__((ext_vector_type(8))) short short8; // 8 bf16 MFMA A/B frag
typedef __attribute__((ext_vector_type(4))) float f32x4;  // MFMA C/D frag

__device__ __forceinline__ float bflo(u32 w) { return __uint_as_float(w << 16); }
__device__ __forceinline__ float bfhi(u32 w) { return __uint_as_float(w & 0xffff0000u); }
__device__ __forceinline__ ushort_t f2bf(float f) { // round-to-nearest-even
  u32 u = __float_as_uint(f);
  u += 0x7fffu + ((u >> 16) & 1u);
  return (ushort_t)(u >> 16);
}

// ---------------- fp32 -> bf16 bulk conversion ---------------------------------
__global__ __launch_bounds__(256) void k_f2bf(const float* __restrict__ src,
                                              ushort_t* __restrict__ dst, int n4) {
  int i = blockIdx.x * 256 + threadIdx.x;
  if (i < n4) {
    float4 v = ((const float4*)src)[i];
    ushort4 o;
    o.x = f2bf(v.x); o.y = f2bf(v.y); o.z = f2bf(v.z); o.w = f2bf(v.w);
    ((ushort4*)dst)[i] = o;
  }
}

// ---------------- pack qkv weights [12][3*64][64] bf16 + bias [12][192] fp32 ----
__global__ __launch_bounds__(256) void k_pack_qkv(
    const float* __restrict__ Wq, const float* __restrict__ Wk,
    const float* __restrict__ Wv, const float* __restrict__ bq,
    const float* __restrict__ bk, const float* __restrict__ bv,
    ushort_t* __restrict__ Wc, float* __restrict__ bc)
{
  int i = blockIdx.x * 256 + threadIdx.x; // 0 .. 147455
  int h = i / 12288, rem = i - h * 12288;
  int mat = rem / 4096, w = rem - mat * 4096;
  const float* src = (mat == 0) ? Wq : ((mat == 1) ? Wk : Wv);
  Wc[i] = f2bf(src[h * 4096 + w]);
  if (i < Hn * 192) {
    int h2 = i / 192, r2 = i - h2 * 192;
    int m2 = r2 / 64, e2 = r2 - m2 * 64;
    const float* bs = (m2 == 0) ? bq : ((m2 == 1) ? bk : bv);
    bc[i] = bs[h2 * 64 + e2];
  }
}

// ---------------- kernel 1: LN1 -> bf16 (one WG per token) ---------------------
__global__ __launch_bounds__(256) void k_ln1(
    const float* __restrict__ x, const float* __restrict__ g1,
    const float* __restrict__ be1, ushort_t* __restrict__ hb)
{
  const int t = blockIdx.x, tid = threadIdx.x;
  __shared__ float red[8];
  float xv[3];
#pragma unroll
  for (int i = 0; i < 3; i++) xv[i] = x[(size_t)t * Dn + tid + i * 256];
  float s = xv[0] + xv[1] + xv[2];
#pragma unroll
  for (int off = 32; off > 0; off >>= 1) s += __shfl_down(s, off, 64);
  if ((tid & 63) == 0) red[tid >> 6] = s;
  __syncthreads();
  float mean = (red[0] + red[1] + red[2] + red[3]) * (1.0f / 768.0f);
  float d0 = xv[0] - mean, d1 = xv[1] - mean, d2 = xv[2] - mean;
  float s2 = d0 * d0 + d1 * d1 + d2 * d2;
#pragma unroll
  for (int off = 32; off > 0; off >>= 1) s2 += __shfl_down(s2, off, 64);
  if ((tid & 63) == 0) red[4 + (tid >> 6)] = s2;
  __syncthreads();
  float rstd = rsqrtf((red[4] + red[5] + red[6] + red[7]) * (1.0f / 768.0f) + 1e-5f);
#pragma unroll
  for (int i = 0; i < 3; i++) {
    int d = tid + i * 256;
    hb[(size_t)t * Dn + d] = f2bf((xv[i] - mean) * rstd * g1[d] + be1[d]);
  }
}

// ---------------- kernel 2: QKV projection via MFMA ----------------------------
// One WG per (b, head, token-half): M=128 tokens, N=192 (q|k|v), K=64.
// V is written TRANSPOSED: vt[bh][e][s] (r-contiguous -> ushort4 stores).
__global__ __launch_bounds__(256) void k_qkv(
    const ushort_t* __restrict__ hb,  // [NT][768] bf16
    const ushort_t* __restrict__ Wc,  // [12][192][64] bf16
    const float* __restrict__ bc,     // [12][192] fp32
    ushort_t* __restrict__ qo, ushort_t* __restrict__ ko, ushort_t* __restrict__ vt)
{
  __shared__ __align__(16) ushort_t As[128 * 72];
  __shared__ __align__(16) ushort_t Ws[192 * 72];
  const int blk = blockIdx.x;         // (b*12 + h)*2 + half
  const int half = blk & 1;
  const int bh = blk >> 1;
  const int b_ = bh / Hn, h_ = bh - b_ * Hn;
  const int tid = threadIdx.x;
  const int t0 = b_ * Sn + half * 128;

  { // stage A: 128 rows x 64 cols (head slice of hb)
    int row = tid >> 1, seg = (tid & 1) * 32;
    const uint4* g = (const uint4*)(hb + (size_t)(t0 + row) * Dn + h_ * 64 + seg);
    uint4* s = (uint4*)(As + row * 72 + seg);
    s[0] = g[0]; s[1] = g[1]; s[2] = g[2]; s[3] = g[3];
  }
  { // stage W: 192 rows x 64 cols, contiguous per head
    int rr = tid >> 2, seg = (tid & 3) * 16;
    const ushort_t* gw = Wc + h_ * 12288;
#pragma unroll
    for (int p = 0; p < 3; p++) {
      int R = p * 64 + rr;
      const uint4* g = (const uint4*)(gw + R * 64 + seg);
      uint4* s = (uint4*)(Ws + R * 72 + seg);
      s[0] = g[0]; s[1] = g[1];
    }
  }
  __syncthreads();

  const int wave = tid >> 6, lane = tid & 63;
  const int wm = (wave >> 1) * 64, wn = (wave & 1) * 96;
  const int lrow = lane & 15, quad = lane >> 4;

  f32x4 acc[4][6];
#pragma unroll
  for (int mi = 0; mi < 4; mi++)
#pragma unroll
    for (int ni = 0; ni < 6; ni++) acc[mi][ni] = (f32x4){0.f, 0.f, 0.f, 0.f};

#pragma unroll
  for (int kk = 0; kk < 2; kk++) {
    short8 af[4], wf[6];
#pragma unroll
    for (int mi = 0; mi < 4; mi++)
      af[mi] = *(const short8*)(As + (wm + mi * 16 + lrow) * 72 + kk * 32 + quad * 8);
#pragma unroll
    for (int ni = 0; ni < 6; ni++)
      wf[ni] = *(const short8*)(Ws + (wn + ni * 16 + lrow) * 72 + kk * 32 + quad * 8);
#pragma unroll
    for (int mi = 0; mi < 4; mi++)
#pragma unroll
      for (int ni = 0; ni < 6; ni++)
        acc[mi][ni] = __builtin_amdgcn_mfma_f32_16x16x32_bf16(af[mi], wf[ni], acc[mi][ni], 0, 0, 0);
  }

#pragma unroll
  for (int ni = 0; ni < 6; ni++) {
    int c = wn + ni * 16 + lrow;        // 0..191, mat uniform per (wave,ni)
    int mat = c >> 6, e = c & 63;
    float bb = bc[h_ * 192 + c];
    if (mat < 2) {
      ushort_t* dst = (mat == 0) ? qo : ko;
      size_t base = (((size_t)bh) * Sn + half * 128 + wm) * HDn + e;
#pragma unroll
      for (int mi = 0; mi < 4; mi++) {
#pragma unroll
        for (int r = 0; r < 4; r++) {
          int lr = mi * 16 + quad * 4 + r;
          dst[base + (size_t)lr * HDn] = f2bf(acc[mi][ni][r] + bb);
        }
      }
    } else {
      // transposed V: vt[(bh*64 + e)*256 + s], s = half*128 + wm + mi*16 + quad*4 + r
      size_t rowb = ((size_t)bh * 64 + e) * Sn + half * 128 + wm + quad * 4;
#pragma unroll
      for (int mi = 0; mi < 4; mi++) {
        ushort4 pk;
        pk.x = f2bf(acc[mi][ni][0] + bb);
        pk.y = f2bf(acc[mi][ni][1] + bb);
        pk.z = f2bf(acc[mi][ni][2] + bb);
        pk.w = f2bf(acc[mi][ni][3] + bb);
        *(ushort4*)(vt + rowb + mi * 16) = pk;
      }
    }
  }
}

// ---------------- kernel 3: MFMA flash attention -------------------------------
// WG = 256 thr = 4 waves per (b,h,quarter). Wave owns 16 q rows. Keys chunked 64.
// QK^T mfma -> online softmax on C-frags (16-lane shfl reduce, 1/8 in exp arg)
// -> P via per-wave LDS round-trip to A-layout -> PV mfma with Vt from LDS.
__global__ __launch_bounds__(256) void k_attn(
    const ushort_t* __restrict__ q,   // [bh][s][64]
    const ushort_t* __restrict__ kg_, // [bh][s][64]
    const ushort_t* __restrict__ vt,  // [bh][e=64][s=256]
    const float* __restrict__ x,
    float* __restrict__ out1)
{
  __shared__ __align__(16) ushort_t Ks[64 * 72];
  __shared__ __align__(16) ushort_t Vts[64 * 264];
  __shared__ __align__(16) ushort_t Pw[4][16 * 72];
  const int blk = blockIdx.x;          // bh*4 + quarter
  const int qtr = blk & 3, bh = blk >> 2;
  const int b_ = bh / Hn, h_ = bh - b_ * Hn;
  const int tid = threadIdx.x, wave = tid >> 6, lane = tid & 63;
  const int lr16 = lane & 15, quad = lane >> 4;
  const int s0 = qtr * 64 + wave * 16; // wave's first q row (within sequence)

  { // stage Vt whole head: [64][256] -> LDS stride 264
    int r = tid >> 2, cseg = (tid & 3) * 64;
    const uint4* g = (const uint4*)(vt + ((size_t)bh * 64 + r) * Sn + cseg);
    uint4* s = (uint4*)(Vts + r * 264 + cseg);
#pragma unroll
    for (int i = 0; i < 8; i++) s[i] = g[i];
  }

  // Q A-frags (2 x K=32) straight from global
  short8 qf[2];
  {
    const ushort_t* qg = q + ((size_t)bh * Sn + s0 + lr16) * HDn + quad * 8;
    qf[0] = *(const short8*)(qg);
    qf[1] = *(const short8*)(qg + 32);
  }

  f32x4 of[4];
#pragma unroll
  for (int et = 0; et < 4; et++) of[et] = (f32x4){0.f, 0.f, 0.f, 0.f};
  float mrow[4] = {-3.0e38f, -3.0e38f, -3.0e38f, -3.0e38f};
  float lsum[4] = {0.f, 0.f, 0.f, 0.f};

  const ushort_t* kgb = kg_ + (size_t)bh * Sn * HDn;

  for (int c = 0; c < 4; c++) {
    if (c) __syncthreads();
    { // stage K chunk [64][64] -> LDS stride 72
      int row = tid >> 2, seg = (tid & 3) * 16;
      const uint4* g = (const uint4*)(kgb + (size_t)(c * 64 + row) * HDn + seg);
      uint4* s = (uint4*)(Ks + row * 72 + seg);
      s[0] = g[0]; s[1] = g[1];
    }
    __syncthreads();

    // QK^T: sc[ni][r] = S[q=quad*4+r][key = c*64 + ni*16 + lr16]
    f32x4 sc[4];
#pragma unroll
    for (int ni = 0; ni < 4; ni++) sc[ni] = (f32x4){0.f, 0.f, 0.f, 0.f};
#pragma unroll
    for (int kk = 0; kk < 2; kk++) {
#pragma unroll
      for (int ni = 0; ni < 4; ni++) {
        short8 kf = *(const short8*)(Ks + (ni * 16 + lr16) * 72 + kk * 32 + quad * 8);
        sc[ni] = __builtin_amdgcn_mfma_f32_16x16x32_bf16(qf[kk], kf, sc[ni], 0, 0, 0);
      }
    }

    // online softmax (scale 1/8 folded into exp arg)
    float alpha[4];
#pragma unroll
    for (int r = 0; r < 4; r++) {
      float m_ = fmaxf(fmaxf(sc[0][r], sc[1][r]), fmaxf(sc[2][r], sc[3][r]));
#pragma unroll
      for (int msk = 8; msk >= 1; msk >>= 1) m_ = fmaxf(m_, __shfl_xor(m_, msk, 64));
      float mn = fmaxf(mrow[r], m_);
      alpha[r] = __expf((mrow[r] - mn) * 0.125f);
      mrow[r] = mn;
    }
#pragma unroll
    for (int ni = 0; ni < 4; ni++) {
#pragma unroll
      for (int r = 0; r < 4; r++) {
        float p = __expf((sc[ni][r] - mrow[r]) * 0.125f);
        sc[ni][r] = p;
        Pw[wave][(quad * 4 + r) * 72 + ni * 16 + lr16] = f2bf(p);
      }
    }
#pragma unroll
    for (int r = 0; r < 4; r++) {
      float s_ = (sc[0][r] + sc[1][r]) + (sc[2][r] + sc[3][r]);
#pragma unroll
      for (int msk = 8; msk >= 1; msk >>= 1) s_ += __shfl_xor(s_, msk, 64);
      lsum[r] = lsum[r] * alpha[r] + s_;
    }
#pragma unroll
    for (int et = 0; et < 4; et++)
#pragma unroll
      for (int r = 0; r < 4; r++) of[et][r] *= alpha[r];

    // P (A-layout) from private LDS; PV accumulate
    short8 pf0 = *(const short8*)(&Pw[wave][lr16 * 72 + quad * 8]);
    short8 pf1 = *(const short8*)(&Pw[wave][lr16 * 72 + 32 + quad * 8]);
#pragma unroll
    for (int et = 0; et < 4; et++) {
      short8 vf0 = *(const short8*)(Vts + (et * 16 + lr16) * 264 + c * 64 + quad * 8);
      short8 vf1 = *(const short8*)(Vts + (et * 16 + lr16) * 264 + c * 64 + 32 + quad * 8);
      of[et] = __builtin_amdgcn_mfma_f32_16x16x32_bf16(pf0, vf0, of[et], 0, 0, 0);
      of[et] = __builtin_amdgcn_mfma_f32_16x16x32_bf16(pf1, vf1, of[et], 0, 0, 0);
    }
  }

  // epilogue: O/l + x -> out1 (fp32)
  const size_t obase = ((size_t)b_ * Sn + s0) * Dn + h_ * 64;
#pragma unroll
  for (int r = 0; r < 4; r++) {
    float rl = 1.0f / lsum[r];
    int row = quad * 4 + r;
#pragma unroll
    for (int et = 0; et < 4; et++) {
      size_t idx = obase + (size_t)row * Dn + et * 16 + lr16;
      out1[idx] = of[et][r] * rl + x[idx];
    }
  }
}

// ---------------- kernel 4: LN2 (one WG per token) -----------------------------
__global__ __launch_bounds__(256) void k_ln2(
    const float* __restrict__ in, const float* __restrict__ g2,
    const float* __restrict__ be2, ushort_t* __restrict__ h2)
{
  const int t = blockIdx.x, tid = threadIdx.x;
  __shared__ float red[8];
  float xv[3];
#pragma unroll
  for (int i = 0; i < 3; i++) xv[i] = in[(size_t)t * Dn + tid + i * 256];
  float s = xv[0] + xv[1] + xv[2];
#pragma unroll
  for (int off = 32; off > 0; off >>= 1) s += __shfl_down(s, off, 64);
  if ((tid & 63) == 0) red[tid >> 6] = s;
  __syncthreads();
  float mean = (red[0] + red[1] + red[2] + red[3]) * (1.0f / 768.0f);
  float d0 = xv[0] - mean, d1 = xv[1] - mean, d2 = xv[2] - mean;
  float s2 = d0 * d0 + d1 * d1 + d2 * d2;
#pragma unroll
  for (int off = 32; off > 0; off >>= 1) s2 += __shfl_down(s2, off, 64);
  if ((tid & 63) == 0) red[4 + (tid >> 6)] = s2;
  __syncthreads();
  float rstd = rsqrtf((red[4] + red[5] + red[6] + red[7]) * (1.0f / 768.0f) + 1e-5f);
#pragma unroll
  for (int i = 0; i < 3; i++) {
    int d = tid + i * 256;
    h2[(size_t)t * Dn + d] = f2bf((xv[i] - mean) * rstd * g2[d] + be2[d]);
  }
}

// ---------------- kernels 5/6: bf16 MFMA GEMM, C[M,N] = A[M,K] * B[N,K]^T ------
template <int KDIM, bool GELU>
__global__ __launch_bounds__(256) void k_gemm_bt(
    const ushort_t* __restrict__ A,   // [M][KDIM] bf16
    const ushort_t* __restrict__ Bw,  // [N][KDIM] bf16
    const float* __restrict__ bias,   // [N] fp32
    const float* __restrict__ res,    // [M][N] fp32 residual (GELU=false only)
    ushort_t* __restrict__ CoutB,     // bf16 out (GELU=true)
    float* __restrict__ CoutF,        // fp32 out (GELU=false)
    int N)
{
  __shared__ __align__(16) ushort_t As[128 * 40];
  __shared__ __align__(16) ushort_t Bs[128 * 40];
  const int tid = threadIdx.x;
  const int m0 = blockIdx.y * 128, n0 = blockIdx.x * 128;
  const int wave = tid >> 6, lane = tid & 63;
  const int wm = (wave >> 1) << 6, wn = (wave & 1) << 6;
  const int lrow = lane & 15, quad = lane >> 4;
  const int arow = tid >> 1, aseg = (tid & 1) << 4;

  f32x4 acc[4][4];
#pragma unroll
  for (int mi = 0; mi < 4; mi++)
#pragma unroll
    for (int ni = 0; ni < 4; ni++) acc[mi][ni] = (f32x4){0.f, 0.f, 0.f, 0.f};

  const uint4* gA = (const uint4*)(A + (size_t)(m0 + arow) * KDIM + aseg);
  const uint4* gB = (const uint4*)(Bw + (size_t)(n0 + arow) * KDIM + aseg);
  uint4* sA = (uint4*)(As + arow * 40 + aseg);
  uint4* sB = (uint4*)(Bs + arow * 40 + aseg);

  for (int k0 = 0; k0 < KDIM; k0 += 32) {
    uint4 a0 = gA[0], a1 = gA[1];
    uint4 b0 = gB[0], b1 = gB[1];
    gA += 4; gB += 4;
    sA[0] = a0; sA[1] = a1;
    sB[0] = b0; sB[1] = b1;
    __syncthreads();
    short8 af[4], bfv[4];
#pragma unroll
    for (int mi = 0; mi < 4; mi++)
      af[mi] = *(const short8*)(As + (wm + mi * 16 + lrow) * 40 + quad * 8);
#pragma unroll
    for (int ni = 0; ni < 4; ni++)
      bfv[ni] = *(const short8*)(Bs + (wn + ni * 16 + lrow) * 40 + quad * 8);
#pragma unroll
    for (int mi = 0; mi < 4; mi++)
#pragma unroll
      for (int ni = 0; ni < 4; ni++)
        acc[mi][ni] = __builtin_amdgcn_mfma_f32_16x16x32_bf16(af[mi], bfv[ni], acc[mi][ni], 0, 0, 0);
    __syncthreads();
  }

#pragma unroll
  for (int ni = 0; ni < 4; ni++) {
    int col = n0 + wn + ni * 16 + lrow;
    float bc = bias[col];
#pragma unroll
    for (int mi = 0; mi < 4; mi++) {
#pragma unroll
      for (int r = 0; r < 4; r++) {
        int row = m0 + wm + mi * 16 + quad * 4 + r;
        float vv = acc[mi][ni][r] + bc;
        if (GELU) {
          float o = 0.5f * vv * (1.0f + erff(vv * 0.70710678f));
          CoutB[(size_t)row * N + col] = f2bf(o);
        } else {
          CoutF[(size_t)row * N + col] = vv + res[(size_t)row * N + col];
        }
      }
    }
  }
}

// ---------------- launch --------------------------------------------------------
extern "C" void kernel_launch(void* const* d_in, const int* in_sizes, int n_in,
                              void* d_out, int out_size, void* d_ws, size_t ws_size,
                              hipStream_t stream) {
  (void)in_sizes; (void)n_in; (void)out_size; (void)ws_size;
  const float* x   = (const float*)d_in[0];
  const float* g1  = (const float*)d_in[1];
  const float* be1 = (const float*)d_in[2];
  const float* Wq  = (const float*)d_in[3];
  const float* bq  = (const float*)d_in[4];
  const float* Wk  = (const float*)d_in[5];
  const float* bk  = (const float*)d_in[6];
  const float* Wv  = (const float*)d_in[7];
  const float* bv  = (const float*)d_in[8];
  const float* g2  = (const float*)d_in[9];
  const float* be2 = (const float*)d_in[10];
  const float* W1  = (const float*)d_in[11];
  const float* bm1 = (const float*)d_in[12];
  const float* W2  = (const float*)d_in[13];
  const float* bm2 = (const float*)d_in[14];
  float* outp = (float*)d_out;

  char* ws = (char*)d_ws;
  float*    out1 = (float*)ws;                   // [0, 25165824)
  ushort_t* hb   = (ushort_t*)ws;                // bf16 h, pre-attn only
  ushort_t* qb   = (ushort_t*)(ws + 25165824);
  ushort_t* kb   = (ushort_t*)(ws + 37748736);
  ushort_t* vtb  = (ushort_t*)(ws + 50331648);   // V transposed [bh][64][256]
  ushort_t* h2   = qb;                           // reuse q after attn
  ushort_t* mb   = (ushort_t*)(ws + 37748736);   // overlays k,vt
  ushort_t* Wc   = (ushort_t*)(ws + 88080384);
  ushort_t* W1b  = (ushort_t*)(ws + 88375296);
  ushort_t* W2b  = (ushort_t*)(ws + 93093888);
  float*    bcb  = (float*)(ws + 97812480);

  const int nW1 = MLPn * Dn; // 2359296
  k_pack_qkv<<<dim3(576), dim3(256), 0, stream>>>(Wq, Wk, Wv, bq, bk, bv, Wc, bcb);
  k_f2bf<<<dim3(nW1 / 4 / 256), dim3(256), 0, stream>>>(W1, W1b, nW1 / 4);
  k_f2bf<<<dim3(nW1 / 4 / 256), dim3(256), 0, stream>>>(W2, W2b, nW1 / 4);

  k_ln1<<<dim3(NT), dim3(256), 0, stream>>>(x, g1, be1, hb);
  k_qkv<<<dim3(Bn * Hn * 2), dim3(256), 0, stream>>>(hb, Wc, bcb, qb, kb, vtb);
  k_attn<<<dim3(Bn * Hn * 4), dim3(256), 0, stream>>>(qb, kb, vtb, x, out1);
  k_ln2<<<dim3(NT), dim3(256), 0, stream>>>(out1, g2, be2, h2);
  k_gemm_bt<Dn, true><<<dim3(MLPn / 128, NT / 128), dim3(256), 0, stream>>>(h2, W1b, bm1, nullptr, mb, nullptr, MLPn);
  k_gemm_bt<MLPn, false><<<dim3(Dn / 128, NT / 128), dim3(256), 0, stream>>>(mb, W2b, bm2, out1, nullptr, outp, Dn);
}

// Round 5
// 327.262 us; speedup vs baseline: 2.8321x; 1.2606x over previous
//
#include <hip/hip_runtime.h>
#include <hip/hip_bf16.h>
#include <math.h>

// ViT block, B=32 S=256 D=768 H=12 HD=64 MLP=3072. fp32 I/O, bf16 MFMA inside.
//
// ws layout (total ~97.9 MB):
//   [0,        25165824)  out1 fp32 [8192][768] residual trunk; hb bf16 pre-attn
//   [25165824, 37748736)  q bf16 ; h2 bf16 after attn ; fc2 bf16 partial p0 after fc1
//   [37748736, 50331648)  k  bf16             ; overlaid by mb after attn
//   [50331648, 62914560)  vt bf16 [B,H,64,S]  ; overlaid by mb after attn
//   [37748736, 88080384)  mb bf16 [8192][3072] gelu(fc1)
//   [88080384, 88375296)  Wc  bf16 [12][192][64] packed qkv weights
//   [88375296, 93093888)  W1b bf16 [3072][768]
//   [93093888, 97812480)  W2b bf16 [768][3072]
//   [97812480, 97821696)  bcb fp32 [12][192] packed qkv bias
// fc2 fp32 partial p1 lives in d_out (fully overwritten every call).

static constexpr int Bn = 32, Sn = 256, Dn = 768, Hn = 12, HDn = 64, MLPn = 3072;
static constexpr int NT = Bn * Sn; // 8192 tokens

typedef unsigned short ushort_t;
typedef unsigned int u32;
typedef __attribute__((ext_vector_type(8))) short short8; // 8 bf16 MFMA A/B frag
typedef __attribute__((ext_vector_type(4))) float f32x4;  // MFMA C/D frag

__device__ __forceinline__ float bf2f(ushort_t u) { return __uint_as_float(((u32)u) << 16); }
__device__ __forceinline__ float bflo(u32 w) { return __uint_as_float(w << 16); }
__device__ __forceinline__ float bfhi(u32 w) { return __uint_as_float(w & 0xffff0000u); }
__device__ __forceinline__ ushort_t f2bf(float f) { // round-to-nearest-even
  u32 u = __float_as_uint(f);
  u += 0x7fffu + ((u >> 16) & 1u);
  return (ushort_t)(u >> 16);
}

// async global->LDS 16B per lane; LDS dest = wave-uniform base + lane*16 (m97/m104)
__device__ __forceinline__ void async_cp16(const ushort_t* g, ushort_t* l) {
  __builtin_amdgcn_global_load_lds(
      (const __attribute__((address_space(1))) u32*)g,
      (__attribute__((address_space(3))) u32*)l, 16, 0, 0);
}

// ---------------- fp32 -> bf16 bulk conversion ---------------------------------
__global__ __launch_bounds__(256) void k_f2bf(const float* __restrict__ src,
                                              ushort_t* __restrict__ dst, int n4) {
  int i = blockIdx.x * 256 + threadIdx.x;
  if (i < n4) {
    float4 v = ((const float4*)src)[i];
    ushort4 o;
    o.x = f2bf(v.x); o.y = f2bf(v.y); o.z = f2bf(v.z); o.w = f2bf(v.w);
    ((ushort4*)dst)[i] = o;
  }
}

// ---------------- pack qkv weights [12][3*64][64] bf16 + bias [12][192] fp32 ----
__global__ __launch_bounds__(256) void k_pack_qkv(
    const float* __restrict__ Wq, const float* __restrict__ Wk,
    const float* __restrict__ Wv, const float* __restrict__ bq,
    const float* __restrict__ bk, const float* __restrict__ bv,
    ushort_t* __restrict__ Wc, float* __restrict__ bc)
{
  int i = blockIdx.x * 256 + threadIdx.x; // 0 .. 147455
  int h = i / 12288, rem = i - h * 12288;
  int mat = rem / 4096, w = rem - mat * 4096;
  const float* src = (mat == 0) ? Wq : ((mat == 1) ? Wk : Wv);
  Wc[i] = f2bf(src[h * 4096 + w]);
  if (i < Hn * 192) {
    int h2 = i / 192, r2 = i - h2 * 192;
    int m2 = r2 / 64, e2 = r2 - m2 * 64;
    const float* bs = (m2 == 0) ? bq : ((m2 == 1) ? bk : bv);
    bc[i] = bs[h2 * 64 + e2];
  }
}

// ---------------- kernel 1: LN1 -> bf16 (one WG per token) ---------------------
__global__ __launch_bounds__(256) void k_ln1(
    const float* __restrict__ x, const float* __restrict__ g1,
    const float* __restrict__ be1, ushort_t* __restrict__ hb)
{
  const int t = blockIdx.x, tid = threadIdx.x;
  __shared__ float red[8];
  float xv[3];
#pragma unroll
  for (int i = 0; i < 3; i++) xv[i] = x[(size_t)t * Dn + tid + i * 256];
  float s = xv[0] + xv[1] + xv[2];
#pragma unroll
  for (int off = 32; off > 0; off >>= 1) s += __shfl_down(s, off, 64);
  if ((tid & 63) == 0) red[tid >> 6] = s;
  __syncthreads();
  float mean = (red[0] + red[1] + red[2] + red[3]) * (1.0f / 768.0f);
  float d0 = xv[0] - mean, d1 = xv[1] - mean, d2 = xv[2] - mean;
  float s2 = d0 * d0 + d1 * d1 + d2 * d2;
#pragma unroll
  for (int off = 32; off > 0; off >>= 1) s2 += __shfl_down(s2, off, 64);
  if ((tid & 63) == 0) red[4 + (tid >> 6)] = s2;
  __syncthreads();
  float rstd = rsqrtf((red[4] + red[5] + red[6] + red[7]) * (1.0f / 768.0f) + 1e-5f);
#pragma unroll
  for (int i = 0; i < 3; i++) {
    int d = tid + i * 256;
    hb[(size_t)t * Dn + d] = f2bf((xv[i] - mean) * rstd * g1[d] + be1[d]);
  }
}

// ---------------- kernel 2: QKV projection via MFMA ----------------------------
__global__ __launch_bounds__(256) void k_qkv(
    const ushort_t* __restrict__ hb,  // [NT][768] bf16
    const ushort_t* __restrict__ Wc,  // [12][192][64] bf16
    const float* __restrict__ bc,     // [12][192] fp32
    ushort_t* __restrict__ qo, ushort_t* __restrict__ ko, ushort_t* __restrict__ vt)
{
  __shared__ __align__(16) ushort_t As[128 * 72];
  __shared__ __align__(16) ushort_t Ws[192 * 72];
  const int blk = blockIdx.x;         // (b*12 + h)*2 + half
  const int half = blk & 1;
  const int bh = blk >> 1;
  const int b_ = bh / Hn, h_ = bh - b_ * Hn;
  const int tid = threadIdx.x;
  const int t0 = b_ * Sn + half * 128;

  { // stage A: 128 rows x 64 cols (head slice of hb)
    int row = tid >> 1, seg = (tid & 1) * 32;
    const uint4* g = (const uint4*)(hb + (size_t)(t0 + row) * Dn + h_ * 64 + seg);
    uint4* s = (uint4*)(As + row * 72 + seg);
    s[0] = g[0]; s[1] = g[1]; s[2] = g[2]; s[3] = g[3];
  }
  { // stage W: 192 rows x 64 cols, contiguous per head
    int rr = tid >> 2, seg = (tid & 3) * 16;
    const ushort_t* gw = Wc + h_ * 12288;
#pragma unroll
    for (int p = 0; p < 3; p++) {
      int R = p * 64 + rr;
      const uint4* g = (const uint4*)(gw + R * 64 + seg);
      uint4* s = (uint4*)(Ws + R * 72 + seg);
      s[0] = g[0]; s[1] = g[1];
    }
  }
  __syncthreads();

  const int wave = tid >> 6, lane = tid & 63;
  const int wm = (wave >> 1) * 64, wn = (wave & 1) * 96;
  const int lrow = lane & 15, quad = lane >> 4;

  f32x4 acc[4][6];
#pragma unroll
  for (int mi = 0; mi < 4; mi++)
#pragma unroll
    for (int ni = 0; ni < 6; ni++) acc[mi][ni] = (f32x4){0.f, 0.f, 0.f, 0.f};

#pragma unroll
  for (int kk = 0; kk < 2; kk++) {
    short8 af[4], wf[6];
#pragma unroll
    for (int mi = 0; mi < 4; mi++)
      af[mi] = *(const short8*)(As + (wm + mi * 16 + lrow) * 72 + kk * 32 + quad * 8);
#pragma unroll
    for (int ni = 0; ni < 6; ni++)
      wf[ni] = *(const short8*)(Ws + (wn + ni * 16 + lrow) * 72 + kk * 32 + quad * 8);
#pragma unroll
    for (int mi = 0; mi < 4; mi++)
#pragma unroll
      for (int ni = 0; ni < 6; ni++)
        acc[mi][ni] = __builtin_amdgcn_mfma_f32_16x16x32_bf16(af[mi], wf[ni], acc[mi][ni], 0, 0, 0);
  }

#pragma unroll
  for (int ni = 0; ni < 6; ni++) {
    int c = wn + ni * 16 + lrow;        // 0..191, mat uniform per (wave,ni)
    int mat = c >> 6, e = c & 63;
    float bb = bc[h_ * 192 + c];
    if (mat < 2) {
      ushort_t* dst = (mat == 0) ? qo : ko;
      size_t base = (((size_t)bh) * Sn + half * 128 + wm) * HDn + e;
#pragma unroll
      for (int mi = 0; mi < 4; mi++) {
#pragma unroll
        for (int r = 0; r < 4; r++) {
          int lr = mi * 16 + quad * 4 + r;
          dst[base + (size_t)lr * HDn] = f2bf(acc[mi][ni][r] + bb);
        }
      }
    } else {
      size_t rowb = ((size_t)bh * 64 + e) * Sn + half * 128 + wm + quad * 4;
#pragma unroll
      for (int mi = 0; mi < 4; mi++) {
        ushort4 pk;
        pk.x = f2bf(acc[mi][ni][0] + bb);
        pk.y = f2bf(acc[mi][ni][1] + bb);
        pk.z = f2bf(acc[mi][ni][2] + bb);
        pk.w = f2bf(acc[mi][ni][3] + bb);
        *(ushort4*)(vt + rowb + mi * 16) = pk;
      }
    }
  }
}

// ---------------- kernel 3: MFMA flash attention -------------------------------
__global__ __launch_bounds__(256) void k_attn(
    const ushort_t* __restrict__ q,   // [bh][s][64]
    const ushort_t* __restrict__ kg_, // [bh][s][64]
    const ushort_t* __restrict__ vt,  // [bh][e=64][s=256]
    const float* __restrict__ x,
    float* __restrict__ out1)
{
  __shared__ __align__(16) ushort_t Ks[64 * 72];
  __shared__ __align__(16) ushort_t Vts[64 * 264];
  __shared__ __align__(16) ushort_t Pw[4][16 * 72];
  const int blk = blockIdx.x;          // bh*4 + quarter
  const int qtr = blk & 3, bh = blk >> 2;
  const int b_ = bh / Hn, h_ = bh - b_ * Hn;
  const int tid = threadIdx.x, wave = tid >> 6, lane = tid & 63;
  const int lr16 = lane & 15, quad = lane >> 4;
  const int s0 = qtr * 64 + wave * 16;

  { // stage Vt whole head
    int r = tid >> 2, cseg = (tid & 3) * 64;
    const uint4* g = (const uint4*)(vt + ((size_t)bh * 64 + r) * Sn + cseg);
    uint4* s = (uint4*)(Vts + r * 264 + cseg);
#pragma unroll
    for (int i = 0; i < 8; i++) s[i] = g[i];
  }

  short8 qf[2];
  {
    const ushort_t* qg = q + ((size_t)bh * Sn + s0 + lr16) * HDn + quad * 8;
    qf[0] = *(const short8*)(qg);
    qf[1] = *(const short8*)(qg + 32);
  }

  f32x4 of[4];
#pragma unroll
  for (int et = 0; et < 4; et++) of[et] = (f32x4){0.f, 0.f, 0.f, 0.f};
  float mrow[4] = {-3.0e38f, -3.0e38f, -3.0e38f, -3.0e38f};
  float lsum[4] = {0.f, 0.f, 0.f, 0.f};

  const ushort_t* kgb = kg_ + (size_t)bh * Sn * HDn;

  for (int c = 0; c < 4; c++) {
    if (c) __syncthreads();
    {
      int row = tid >> 2, seg = (tid & 3) * 16;
      const uint4* g = (const uint4*)(kgb + (size_t)(c * 64 + row) * HDn + seg);
      uint4* s = (uint4*)(Ks + row * 72 + seg);
      s[0] = g[0]; s[1] = g[1];
    }
    __syncthreads();

    f32x4 sc[4];
#pragma unroll
    for (int ni = 0; ni < 4; ni++) sc[ni] = (f32x4){0.f, 0.f, 0.f, 0.f};
#pragma unroll
    for (int kk = 0; kk < 2; kk++) {
#pragma unroll
      for (int ni = 0; ni < 4; ni++) {
        short8 kf = *(const short8*)(Ks + (ni * 16 + lr16) * 72 + kk * 32 + quad * 8);
        sc[ni] = __builtin_amdgcn_mfma_f32_16x16x32_bf16(qf[kk], kf, sc[ni], 0, 0, 0);
      }
    }

    float alpha[4];
#pragma unroll
    for (int r = 0; r < 4; r++) {
      float m_ = fmaxf(fmaxf(sc[0][r], sc[1][r]), fmaxf(sc[2][r], sc[3][r]));
#pragma unroll
      for (int msk = 8; msk >= 1; msk >>= 1) m_ = fmaxf(m_, __shfl_xor(m_, msk, 64));
      float mn = fmaxf(mrow[r], m_);
      alpha[r] = __expf((mrow[r] - mn) * 0.125f);
      mrow[r] = mn;
    }
#pragma unroll
    for (int ni = 0; ni < 4; ni++) {
#pragma unroll
      for (int r = 0; r < 4; r++) {
        float p = __expf((sc[ni][r] - mrow[r]) * 0.125f);
        sc[ni][r] = p;
        Pw[wave][(quad * 4 + r) * 72 + ni * 16 + lr16] = f2bf(p);
      }
    }
#pragma unroll
    for (int r = 0; r < 4; r++) {
      float s_ = (sc[0][r] + sc[1][r]) + (sc[2][r] + sc[3][r]);
#pragma unroll
      for (int msk = 8; msk >= 1; msk >>= 1) s_ += __shfl_xor(s_, msk, 64);
      lsum[r] = lsum[r] * alpha[r] + s_;
    }
#pragma unroll
    for (int et = 0; et < 4; et++)
#pragma unroll
      for (int r = 0; r < 4; r++) of[et][r] *= alpha[r];

    short8 pf0 = *(const short8*)(&Pw[wave][lr16 * 72 + quad * 8]);
    short8 pf1 = *(const short8*)(&Pw[wave][lr16 * 72 + 32 + quad * 8]);
#pragma unroll
    for (int et = 0; et < 4; et++) {
      short8 vf0 = *(const short8*)(Vts + (et * 16 + lr16) * 264 + c * 64 + quad * 8);
      short8 vf1 = *(const short8*)(Vts + (et * 16 + lr16) * 264 + c * 64 + 32 + quad * 8);
      of[et] = __builtin_amdgcn_mfma_f32_16x16x32_bf16(pf0, vf0, of[et], 0, 0, 0);
      of[et] = __builtin_amdgcn_mfma_f32_16x16x32_bf16(pf1, vf1, of[et], 0, 0, 0);
    }
  }

  const size_t obase = ((size_t)b_ * Sn + s0) * Dn + h_ * 64;
#pragma unroll
  for (int r = 0; r < 4; r++) {
    float rl = 1.0f / lsum[r];
    int row = quad * 4 + r;
#pragma unroll
    for (int et = 0; et < 4; et++) {
      size_t idx = obase + (size_t)row * Dn + et * 16 + lr16;
      out1[idx] = of[et][r] * rl + x[idx];
    }
  }
}

// ---------------- kernel 4: LN2 (one WG per token) -----------------------------
__global__ __launch_bounds__(256) void k_ln2(
    const float* __restrict__ in, const float* __restrict__ g2,
    const float* __restrict__ be2, ushort_t* __restrict__ h2)
{
  const int t = blockIdx.x, tid = threadIdx.x;
  __shared__ float red[8];
  float xv[3];
#pragma unroll
  for (int i = 0; i < 3; i++) xv[i] = in[(size_t)t * Dn + tid + i * 256];
  float s = xv[0] + xv[1] + xv[2];
#pragma unroll
  for (int off = 32; off > 0; off >>= 1) s += __shfl_down(s, off, 64);
  if ((tid & 63) == 0) red[tid >> 6] = s;
  __syncthreads();
  float mean = (red[0] + red[1] + red[2] + red[3]) * (1.0f / 768.0f);
  float d0 = xv[0] - mean, d1 = xv[1] - mean, d2 = xv[2] - mean;
  float s2 = d0 * d0 + d1 * d1 + d2 * d2;
#pragma unroll
  for (int off = 32; off > 0; off >>= 1) s2 += __shfl_down(s2, off, 64);
  if ((tid & 63) == 0) red[4 + (tid >> 6)] = s2;
  __syncthreads();
  float rstd = rsqrtf((red[4] + red[5] + red[6] + red[7]) * (1.0f / 768.0f) + 1e-5f);
#pragma unroll
  for (int i = 0; i < 3; i++) {
    int d = tid + i * 256;
    h2[(size_t)t * Dn + d] = f2bf((xv[i] - mean) * rstd * g2[d] + be2[d]);
  }
}

// ------- kernels 5/6: m97-style MFMA GEMM w/ global_load_lds, C = A * B^T ------
// 128x128 tile, BK=32, unpadded LDS stride 32 (required by global_load_lds).
// GELU=true: +bias, exact-erf GELU -> bf16. PARTIAL=true: split-K over gridDim.z,
// z=0 -> bf16 partial (CoutB), z=1 -> fp32 partial (CoutF); no bias.
template <int KDIM, bool GELU, bool PARTIAL>
__global__ __launch_bounds__(256) void k_gemm_lds(
    const ushort_t* __restrict__ A,   // [M][KDIM] bf16
    const ushort_t* __restrict__ Bw,  // [N][KDIM] bf16
    const float* __restrict__ bias,   // [N] fp32 (GELU only)
    ushort_t* __restrict__ CoutB,     // bf16 out
    float* __restrict__ CoutF,        // fp32 out
    int N)
{
  __shared__ __align__(16) ushort_t As[128 * 32];
  __shared__ __align__(16) ushort_t Bs[128 * 32];
  const int tid = threadIdx.x;
  const int m0 = blockIdx.y * 128, n0 = blockIdx.x * 128;
  const int wave = tid >> 6, lane = tid & 63;
  const int wm = (wave >> 1) << 6, wn = (wave & 1) << 6;
  const int lrow = lane & 15, quad = lane >> 4;
  const int lrow4 = lane >> 2, lcol8 = (lane & 3) * 8; // async staging coords

  f32x4 acc[4][4];
#pragma unroll
  for (int mi = 0; mi < 4; mi++)
#pragma unroll
    for (int ni = 0; ni < 4; ni++) acc[mi][ni] = (f32x4){0.f, 0.f, 0.f, 0.f};

  const int kbeg = PARTIAL ? blockIdx.z * (KDIM / 2) : 0;
  const int kend = kbeg + (PARTIAL ? KDIM / 2 : KDIM);

  for (int k0 = kbeg; k0 < kend; k0 += 32) {
    // async stage: per wave 2 A-rows-of-16 + 2 B-rows-of-16 (1024B each instr)
#pragma unroll
    for (int a = 0; a < 2; a++) {
      int rr = wave * 16 + a * 64;
      async_cp16(A + (size_t)(m0 + rr + lrow4) * KDIM + k0 + lcol8, As + rr * 32);
      async_cp16(Bw + (size_t)(n0 + rr + lrow4) * KDIM + k0 + lcol8, Bs + rr * 32);
    }
    __syncthreads();
    short8 af[4], bfv[4];
#pragma unroll
    for (int mi = 0; mi < 4; mi++)
      af[mi] = *(const short8*)(As + (wm + mi * 16 + lrow) * 32 + quad * 8);
#pragma unroll
    for (int ni = 0; ni < 4; ni++)
      bfv[ni] = *(const short8*)(Bs + (wn + ni * 16 + lrow) * 32 + quad * 8);
#pragma unroll
    for (int mi = 0; mi < 4; mi++)
#pragma unroll
      for (int ni = 0; ni < 4; ni++)
        acc[mi][ni] = __builtin_amdgcn_mfma_f32_16x16x32_bf16(af[mi], bfv[ni], acc[mi][ni], 0, 0, 0);
    __syncthreads();
  }

#pragma unroll
  for (int ni = 0; ni < 4; ni++) {
    int col = n0 + wn + ni * 16 + lrow;
    float bc = GELU ? bias[col] : 0.f;
#pragma unroll
    for (int mi = 0; mi < 4; mi++) {
#pragma unroll
      for (int r = 0; r < 4; r++) {
        int row = m0 + wm + mi * 16 + quad * 4 + r;
        float vv = acc[mi][ni][r] + bc;
        if (GELU) {
          float o = 0.5f * vv * (1.0f + erff(vv * 0.70710678f));
          CoutB[(size_t)row * N + col] = f2bf(o);
        } else { // PARTIAL
          if (blockIdx.z == 0) CoutB[(size_t)row * N + col] = f2bf(vv);
          else                 CoutF[(size_t)row * N + col] = vv;
        }
      }
    }
  }
}

// ---------------- kernel 7: split-K reduce + bias + residual -------------------
__global__ __launch_bounds__(256) void k_reduce(
    const ushort_t* __restrict__ p0,  // bf16 partial [8192][768]
    const float* __restrict__ p1,     // fp32 partial (aliases out)
    const float* __restrict__ res,    // out1
    const float* __restrict__ bias,   // bm2 [768]
    float* __restrict__ out)
{
  int i4 = blockIdx.x * 256 + threadIdx.x;     // float4 index, 1572864 total
  int col4 = (i4 % 192) * 4;
  float4 o = ((const float4*)p1)[i4];
  float4 r = ((const float4*)res)[i4];
  ushort4 a = ((const ushort4*)p0)[i4];
  o.x += bf2f(a.x) + bias[col4 + 0] + r.x;
  o.y += bf2f(a.y) + bias[col4 + 1] + r.y;
  o.z += bf2f(a.z) + bias[col4 + 2] + r.z;
  o.w += bf2f(a.w) + bias[col4 + 3] + r.w;
  ((float4*)out)[i4] = o;
}

// ---------------- launch --------------------------------------------------------
extern "C" void kernel_launch(void* const* d_in, const int* in_sizes, int n_in,
                              void* d_out, int out_size, void* d_ws, size_t ws_size,
                              hipStream_t stream) {
  (void)in_sizes; (void)n_in; (void)out_size; (void)ws_size;
  const float* x   = (const float*)d_in[0];
  const float* g1  = (const float*)d_in[1];
  const float* be1 = (const float*)d_in[2];
  const float* Wq  = (const float*)d_in[3];
  const float* bq  = (const float*)d_in[4];
  const float* Wk  = (const float*)d_in[5];
  const float* bk  = (const float*)d_in[6];
  const float* Wv  = (const float*)d_in[7];
  const float* bv  = (const float*)d_in[8];
  const float* g2  = (const float*)d_in[9];
  const float* be2 = (const float*)d_in[10];
  const float* W1  = (const float*)d_in[11];
  const float* bm1 = (const float*)d_in[12];
  const float* W2  = (const float*)d_in[13];
  const float* bm2 = (const float*)d_in[14];
  float* outp = (float*)d_out;

  char* ws = (char*)d_ws;
  float*    out1 = (float*)ws;                   // [0, 25165824)
  ushort_t* hb   = (ushort_t*)ws;                // bf16 h, pre-attn only
  ushort_t* qb   = (ushort_t*)(ws + 25165824);
  ushort_t* kb   = (ushort_t*)(ws + 37748736);
  ushort_t* vtb  = (ushort_t*)(ws + 50331648);   // V transposed [bh][64][256]
  ushort_t* h2   = qb;                           // reuse q after attn
  ushort_t* p0   = qb;                           // fc2 bf16 partial after fc1
  ushort_t* mb   = (ushort_t*)(ws + 37748736);   // overlays k,vt
  ushort_t* Wc   = (ushort_t*)(ws + 88080384);
  ushort_t* W1b  = (ushort_t*)(ws + 88375296);
  ushort_t* W2b  = (ushort_t*)(ws + 93093888);
  float*    bcb  = (float*)(ws + 97812480);

  const int nW1 = MLPn * Dn; // 2359296
  k_pack_qkv<<<dim3(576), dim3(256), 0, stream>>>(Wq, Wk, Wv, bq, bk, bv, Wc, bcb);
  k_f2bf<<<dim3(nW1 / 4 / 256), dim3(256), 0, stream>>>(W1, W1b, nW1 / 4);
  k_f2bf<<<dim3(nW1 / 4 / 256), dim3(256), 0, stream>>>(W2, W2b, nW1 / 4);

  k_ln1<<<dim3(NT), dim3(256), 0, stream>>>(x, g1, be1, hb);
  k_qkv<<<dim3(Bn * Hn * 2), dim3(256), 0, stream>>>(hb, Wc, bcb, qb, kb, vtb);
  k_attn<<<dim3(Bn * Hn * 4), dim3(256), 0, stream>>>(qb, kb, vtb, x, out1);
  k_ln2<<<dim3(NT), dim3(256), 0, stream>>>(out1, g2, be2, h2);
  // fc1: [8192][768] x [3072][768]^T -> gelu -> mb bf16
  k_gemm_lds<Dn, true, false><<<dim3(MLPn / 128, NT / 128, 1), dim3(256), 0, stream>>>(
      h2, W1b, bm1, mb, nullptr, MLPn);
  // fc2 split-K=2: z=0 -> p0 bf16 (qb region), z=1 -> fp32 partial in d_out
  k_gemm_lds<MLPn, false, true><<<dim3(Dn / 128, NT / 128, 2), dim3(256), 0, stream>>>(
      mb, W2b, nullptr, p0, outp, Dn);
  k_reduce<<<dim3(NT * Dn / 4 / 256), dim3(256), 0, stream>>>(p0, outp, out1, bm2, outp);
}